// Round 3
// baseline (190.914 us; speedup 1.0000x reference)
//
#include <hip/hip_runtime.h>

#define BATCH 16
#define H 512
#define W 512
#define BH 128
#define BW 128
#define HG 510   // interior rows (buffer rows 0..509 <-> pixel rows 1..510)
#define WG 510
#define PKW 512  // padded row stride of packed intermediate

// pack: (mag_bits & ~31) | o   -- o in [0,18) fits 5 bits; mag rel err ~3e-6
// o is chosen BEFORE truncation, so argmax decisions are bit-identical to ref.

// ---------------- Kernel 1: gradient + orientation, 4 px/thread ----------------
__global__ __launch_bounds__(256) void hog_grad(const float* __restrict__ img,
                                                unsigned int* __restrict__ pk)
{
    int tx = threadIdx.x;
    int gx = blockIdx.x * 64 + tx;          // quad index 0..127
    int y  = blockIdx.y * 4 + threadIdx.y;  // buffer row
    int b  = blockIdx.z;
    if (y >= HG) return;
    int x0 = gx * 4;                        // buffer col of px 0 (0..508); aligned
    int py = y + 1;
    bool edge = (x0 < 508);                 // predicate for the +4 scalar on up/down rows

    const float* im = img + (size_t)b * 3 * H * W;

    float bv[4] = {-1.f, -1.f, -1.f, -1.f};
    float bx[4] = {0, 0, 0, 0};
    float by[4] = {0, 0, 0, 0};

#pragma unroll
    for (int c = 0; c < 3; c++) {
        const float* base = im + (size_t)c * H * W;
        const float* ru = base + (size_t)(py - 1) * W;
        const float* rc = base + (size_t)py * W;
        const float* rd = base + (size_t)(py + 1) * W;
        // all loads 16B/8B aligned; OOB impossible:
        //  - c2 max addr: row<=510, cols 512..513 spill into row 511 (exists)
        //  - us/ds guarded by `edge` so row 511 col 512 never read
        float4 u4 = *(const float4*)(ru + x0);
        float4 c4 = *(const float4*)(rc + x0);
        float2 c2 = *(const float2*)(rc + x0 + 4);
        float4 d4 = *(const float4*)(rd + x0);
        float  us = edge ? ru[x0 + 4] : 0.0f;
        float  ds = edge ? rd[x0 + 4] : 0.0f;

        float dx0 = __fsub_rn(c4.z, c4.x), dx1 = __fsub_rn(c4.w, c4.y);
        float dx2 = __fsub_rn(c2.x, c4.z), dx3 = __fsub_rn(c2.y, c4.w);
        float dy0 = __fsub_rn(d4.y, u4.y), dy1 = __fsub_rn(d4.z, u4.z);
        float dy2 = __fsub_rn(d4.w, u4.w), dy3 = __fsub_rn(ds, us);

        float dxs[4] = {dx0, dx1, dx2, dx3};
        float dys[4] = {dy0, dy1, dy2, dy3};
#pragma unroll
        for (int i = 0; i < 4; i++) {
            float v = __fadd_rn(__fmul_rn(dxs[i], dxs[i]), __fmul_rn(dys[i], dys[i]));
            if (v > bv[i]) { bv[i] = v; bx[i] = dxs[i]; by[i] = dys[i]; }
        }
    }

    const float uu[9] = {1.0f, 0.9397f, 0.766f, 0.5f, 0.1736f, -0.1736f, -0.5f, -0.766f, -0.9397f};
    const float vv[9] = {0.0f, 0.342f, 0.6428f, 0.866f, 0.9848f, 0.9848f, 0.866f, 0.6428f, 0.342f};

    unsigned int pkv[4];
#pragma unroll
    for (int i = 0; i < 4; i++) {
        float mg = __fsqrt_rn(bv[i]);
        float d[9];
#pragma unroll
        for (int o = 0; o < 9; o++)
            d[o] = __fadd_rn(__fmul_rn(uu[o], bx[i]), __fmul_rn(vv[o], by[i]));
        float best = -1e30f; int bo = 0;
#pragma unroll
        for (int o = 0; o < 9; o++) { if (d[o] > best) { best = d[o]; bo = o; } }
#pragma unroll
        for (int o = 0; o < 9; o++) { float nd = -d[o]; if (nd > best) { best = nd; bo = o + 9; } }
        unsigned int v = (__float_as_uint(mg) & 0xFFFFFFE0u) | (unsigned int)bo;
        pkv[i] = (x0 + i < WG) ? v : 0u;   // zero pad cols 510/511
    }
    uint4 o4 = make_uint4(pkv[0], pkv[1], pkv[2], pkv[3]);
    *(uint4*)(pk + ((size_t)b * HG + y) * PKW + x0) = o4;
}

// ---------------- Kernel 2: per-cell 8x8 bilinear gather -> hist + norm ----------------
// LDS accumulation via ds_add_f32 (atomicAdd, result discarded): no
// read-modify-write dependency chain, no barriers (per-thread private columns,
// bank = t%32 -> 2-way aliasing, free).
__global__ __launch_bounds__(256) void hog_hist(const unsigned int* __restrict__ pk,
                                                float* __restrict__ hist,
                                                float* __restrict__ nrm)
{
    __shared__ float hl[18 * 256];
    int cx = threadIdx.x;                   // 0..127
    int cy = blockIdx.y * 2 + threadIdx.y;  // 0..127
    int b = blockIdx.z;
    int t = threadIdx.y * 128 + cx;

#pragma unroll
    for (int o = 0; o < 18; o++) hl[o * 256 + t] = 0.0f;

    const float wt[8] = {0.125f, 0.375f, 0.625f, 0.875f, 0.875f, 0.625f, 0.375f, 0.125f};
    const float wl[4] = {0.0f, 0.125f, 0.375f, 0.625f};   // pixels 4c-4..4c-1
    const float wm[4] = {0.875f, 0.875f, 0.625f, 0.375f}; // pixels 4c..4c+3

    const unsigned int* pb = pk + (size_t)b * HG * PKW;
    int ry0 = 4 * cy - 3;
    int xb = 4 * cx;

#pragma unroll
    for (int ky = 0; ky < 8; ky++) {
        int ry = ry0 + ky;
        if ((unsigned)ry >= (unsigned)HG) continue;  // wave-uniform
        float wy = wt[ky];
        const unsigned int* row = pb + (size_t)ry * PKW;
        if (cx > 0) {
            uint4 L = *(const uint4*)(row + xb - 4);
            { unsigned p = L.y; atomicAdd(&hl[(p & 31u) * 256 + t], (wy * wl[1]) * __uint_as_float(p & 0xFFFFFFE0u)); }
            { unsigned p = L.z; atomicAdd(&hl[(p & 31u) * 256 + t], (wy * wl[2]) * __uint_as_float(p & 0xFFFFFFE0u)); }
            { unsigned p = L.w; atomicAdd(&hl[(p & 31u) * 256 + t], (wy * wl[3]) * __uint_as_float(p & 0xFFFFFFE0u)); }
        }
        uint4 M = *(const uint4*)(row + xb);
        { unsigned p = M.x; atomicAdd(&hl[(p & 31u) * 256 + t], (wy * wm[0]) * __uint_as_float(p & 0xFFFFFFE0u)); }
        { unsigned p = M.y; atomicAdd(&hl[(p & 31u) * 256 + t], (wy * wm[1]) * __uint_as_float(p & 0xFFFFFFE0u)); }
        if (cx < 127) {
            { unsigned p = M.z; atomicAdd(&hl[(p & 31u) * 256 + t], (wy * wm[2]) * __uint_as_float(p & 0xFFFFFFE0u)); }
            { unsigned p = M.w; atomicAdd(&hl[(p & 31u) * 256 + t], (wy * wm[3]) * __uint_as_float(p & 0xFFFFFFE0u)); }
            unsigned p = row[xb + 4];
            atomicAdd(&hl[(p & 31u) * 256 + t], (wy * 0.125f) * __uint_as_float(p & 0xFFFFFFE0u));
        }
    }

    float h[18];
#pragma unroll
    for (int o = 0; o < 18; o++) {
        h[o] = hl[o * 256 + t];
        hist[(((size_t)b * 18 + o) * BH + cy) * BW + cx] = h[o];
    }
    float s = 0.0f;
#pragma unroll
    for (int o = 0; o < 9; o++) { float ss = h[o] + h[o + 9]; s += ss * ss; }
    nrm[((size_t)b * BH + cy) * BW + cx] = s;
}

// ---------------- Kernel 3: normalization + features + zero border ----------------
__global__ __launch_bounds__(256) void hog_feat(const float* __restrict__ hist,
                                                const float* __restrict__ nrm,
                                                float* __restrict__ out)
{
    int ox = threadIdx.x;
    int oy = blockIdx.y * 2 + threadIdx.y;
    int b = blockIdx.z;

    if (ox == 0 || ox == BW - 1 || oy == 0 || oy == BH - 1) {
#pragma unroll
        for (int c = 0; c < 31; c++)
            out[(((size_t)b * 31 + c) * BH + oy) * BW + ox] = 0.0f;
        return;
    }

    const float* nb = nrm + (size_t)b * BH * BW;
    float n00 = nb[(size_t)(oy - 1) * BW + ox - 1], n01 = nb[(size_t)(oy - 1) * BW + ox], n02 = nb[(size_t)(oy - 1) * BW + ox + 1];
    float n10 = nb[(size_t)oy * BW + ox - 1],       n11 = nb[(size_t)oy * BW + ox],       n12 = nb[(size_t)oy * BW + ox + 1];
    float n20 = nb[(size_t)(oy + 1) * BW + ox - 1], n21 = nb[(size_t)(oy + 1) * BW + ox], n22 = nb[(size_t)(oy + 1) * BW + ox + 1];

    float T11 = n11 + n21 + n12 + n22;
    float T01 = n01 + n11 + n02 + n12;
    float T10 = n10 + n20 + n11 + n21;
    float T00 = n00 + n10 + n01 + n11;
    float v1 = 1.0f / __fsqrt_rn(T11 + 1e-4f);
    float v2 = 1.0f / __fsqrt_rn(T01 + 1e-4f);
    float v3 = 1.0f / __fsqrt_rn(T10 + 1e-4f);
    float v4 = 1.0f / __fsqrt_rn(T00 + 1e-4f);

    float h[18];
#pragma unroll
    for (int o = 0; o < 18; o++)
        h[o] = hist[(((size_t)b * 18 + o) * BH + oy) * BW + ox];

    float t1 = 0.f, t2 = 0.f, t3 = 0.f, t4 = 0.f;
#pragma unroll
    for (int o = 0; o < 18; o++) {
        float s = h[o];
        float a1 = fminf(s * v1, 0.2f);
        float a2 = fminf(s * v2, 0.2f);
        float a3 = fminf(s * v3, 0.2f);
        float a4 = fminf(s * v4, 0.2f);
        out[(((size_t)b * 31 + o) * BH + oy) * BW + ox] = 0.5f * (a1 + a2 + a3 + a4);
        t1 += a1; t2 += a2; t3 += a3; t4 += a4;
    }
#pragma unroll
    for (int o = 0; o < 9; o++) {
        float ss = h[o] + h[o + 9];
        float a1 = fminf(ss * v1, 0.2f);
        float a2 = fminf(ss * v2, 0.2f);
        float a3 = fminf(ss * v3, 0.2f);
        float a4 = fminf(ss * v4, 0.2f);
        out[(((size_t)b * 31 + 18 + o) * BH + oy) * BW + ox] = 0.5f * (a1 + a2 + a3 + a4);
    }
    out[(((size_t)b * 31 + 27) * BH + oy) * BW + ox] = 0.2357f * t1;
    out[(((size_t)b * 31 + 28) * BH + oy) * BW + ox] = 0.2357f * t2;
    out[(((size_t)b * 31 + 29) * BH + oy) * BW + ox] = 0.2357f * t3;
    out[(((size_t)b * 31 + 30) * BH + oy) * BW + ox] = 0.2357f * t4;
}

extern "C" void kernel_launch(void* const* d_in, const int* in_sizes, int n_in,
                              void* d_out, int out_size, void* d_ws, size_t ws_size,
                              hipStream_t stream)
{
    const float* img = (const float*)d_in[0];
    float* out = (float*)d_out;
    char* ws = (char*)d_ws;

    // workspace layout (256-aligned offsets):
    //   pk   : 16*510*512*4 = 16,711,680  @ 0
    //   hist : 16*18*128*128*4 = 18,874,368 @ 16,715,776
    //   nrm  : 16*128*128*4 = 1,048,576  @ 35,590,144   (end 36,638,720)
    unsigned int* pk = (unsigned int*)ws;
    float* hist      = (float*)(ws + 16715776);
    float* nrm       = (float*)(ws + 35590144);

    dim3 b1(64, 4, 1), g1(2, 128, BATCH);
    hog_grad<<<g1, b1, 0, stream>>>(img, pk);

    dim3 b2(128, 2, 1), g2(1, BH / 2, BATCH);
    hog_hist<<<g2, b2, 0, stream>>>(pk, hist, nrm);
    hog_feat<<<g2, b2, 0, stream>>>(hist, nrm, out);
}

// Round 4
// 119.292 us; speedup vs baseline: 1.6004x; 1.6004x over previous
//
#include <hip/hip_runtime.h>

#define BATCH 16
#define H 512
#define W 512
#define BH 128
#define BW 128
#define HG 510   // interior rows (buffer rows 0..509 <-> pixel rows 1..510)
#define WG 510
#define PKW 512  // padded row stride of packed intermediate

// pack: (mag_bits & ~31) | o   -- o in [0,18) fits 5 bits; mag rel err ~3e-6
// o is chosen BEFORE truncation, so argmax decisions are bit-identical to ref.

// ---------------- Kernel 1: gradient + orientation, 4 px/thread ----------------
__global__ __launch_bounds__(256) void hog_grad(const float* __restrict__ img,
                                                unsigned int* __restrict__ pk)
{
    int tx = threadIdx.x;
    int gx = blockIdx.x * 64 + tx;          // quad index 0..127
    int y  = blockIdx.y * 4 + threadIdx.y;  // buffer row
    int b  = blockIdx.z;
    if (y >= HG) return;
    int x0 = gx * 4;                        // buffer col of px 0 (0..508); aligned
    int py = y + 1;
    bool edge = (x0 < 508);                 // predicate for the +4 scalar on up/down rows

    const float* im = img + (size_t)b * 3 * H * W;

    float bv[4] = {-1.f, -1.f, -1.f, -1.f};
    float bx[4] = {0, 0, 0, 0};
    float by[4] = {0, 0, 0, 0};

#pragma unroll
    for (int c = 0; c < 3; c++) {
        const float* base = im + (size_t)c * H * W;
        const float* ru = base + (size_t)(py - 1) * W;
        const float* rc = base + (size_t)py * W;
        const float* rd = base + (size_t)(py + 1) * W;
        float4 u4 = *(const float4*)(ru + x0);
        float4 c4 = *(const float4*)(rc + x0);
        float2 c2 = *(const float2*)(rc + x0 + 4);
        float4 d4 = *(const float4*)(rd + x0);
        float  us = edge ? ru[x0 + 4] : 0.0f;
        float  ds = edge ? rd[x0 + 4] : 0.0f;

        float dx0 = __fsub_rn(c4.z, c4.x), dx1 = __fsub_rn(c4.w, c4.y);
        float dx2 = __fsub_rn(c2.x, c4.z), dx3 = __fsub_rn(c2.y, c4.w);
        float dy0 = __fsub_rn(d4.y, u4.y), dy1 = __fsub_rn(d4.z, u4.z);
        float dy2 = __fsub_rn(d4.w, u4.w), dy3 = __fsub_rn(ds, us);

        float dxs[4] = {dx0, dx1, dx2, dx3};
        float dys[4] = {dy0, dy1, dy2, dy3};
#pragma unroll
        for (int i = 0; i < 4; i++) {
            float v = __fadd_rn(__fmul_rn(dxs[i], dxs[i]), __fmul_rn(dys[i], dys[i]));
            if (v > bv[i]) { bv[i] = v; bx[i] = dxs[i]; by[i] = dys[i]; }
        }
    }

    const float uu[9] = {1.0f, 0.9397f, 0.766f, 0.5f, 0.1736f, -0.1736f, -0.5f, -0.766f, -0.9397f};
    const float vv[9] = {0.0f, 0.342f, 0.6428f, 0.866f, 0.9848f, 0.9848f, 0.866f, 0.6428f, 0.342f};

    unsigned int pkv[4];
#pragma unroll
    for (int i = 0; i < 4; i++) {
        float mg = __fsqrt_rn(bv[i]);
        float d[9];
#pragma unroll
        for (int o = 0; o < 9; o++)
            d[o] = __fadd_rn(__fmul_rn(uu[o], bx[i]), __fmul_rn(vv[o], by[i]));
        float best = -1e30f; int bo = 0;
#pragma unroll
        for (int o = 0; o < 9; o++) { if (d[o] > best) { best = d[o]; bo = o; } }
#pragma unroll
        for (int o = 0; o < 9; o++) { float nd = -d[o]; if (nd > best) { best = nd; bo = o + 9; } }
        unsigned int v = (__float_as_uint(mg) & 0xFFFFFFE0u) | (unsigned int)bo;
        pkv[i] = (x0 + i < WG) ? v : 0u;   // zero pad cols 510/511
    }
    uint4 o4 = make_uint4(pkv[0], pkv[1], pkv[2], pkv[3]);
    *(uint4*)(pk + ((size_t)b * HG + y) * PKW + x0) = o4;
}

// ---------------- Kernel 2: per-cell 8x8 bilinear gather -> hist + norm ----------------
// Plain LDS read-add-write (LDS fp32 atomics are ~5x SLOWER on gfx950 -- R3).
// Two private buffers per thread, alternated per pixel: splits the
// compiler-serialized RMW dependency chain into two overlapping chains.
__global__ __launch_bounds__(256) void hog_hist(const unsigned int* __restrict__ pk,
                                                float* __restrict__ hist,
                                                float* __restrict__ nrm)
{
    __shared__ float hl0[18 * 256];
    __shared__ float hl1[18 * 256];
    int cx = threadIdx.x;                   // 0..127
    int cy = blockIdx.y * 2 + threadIdx.y;  // 0..127
    int b = blockIdx.z;
    int t = threadIdx.y * 128 + cx;

#pragma unroll
    for (int o = 0; o < 18; o++) { hl0[o * 256 + t] = 0.0f; hl1[o * 256 + t] = 0.0f; }
    // per-thread private columns: no barrier; bank = t%32 -> 2-way (free)

    const float wt[8] = {0.125f, 0.375f, 0.625f, 0.875f, 0.875f, 0.625f, 0.375f, 0.125f};
    const float wl[4] = {0.0f, 0.125f, 0.375f, 0.625f};   // pixels 4c-4..4c-1
    const float wm[4] = {0.875f, 0.875f, 0.625f, 0.375f}; // pixels 4c..4c+3

    const unsigned int* pb = pk + (size_t)b * HG * PKW;
    int ry0 = 4 * cy - 3;
    int xb = 4 * cx;

#pragma unroll
    for (int ky = 0; ky < 8; ky++) {
        int ry = ry0 + ky;
        if ((unsigned)ry >= (unsigned)HG) continue;  // wave-uniform
        float wy = wt[ky];
        const unsigned int* row = pb + (size_t)ry * PKW;
        if (cx > 0) {
            uint4 L = *(const uint4*)(row + xb - 4);
            { unsigned p = L.y; hl0[(p & 31u) * 256 + t] += (wy * wl[1]) * __uint_as_float(p & 0xFFFFFFE0u); }
            { unsigned p = L.z; hl1[(p & 31u) * 256 + t] += (wy * wl[2]) * __uint_as_float(p & 0xFFFFFFE0u); }
            { unsigned p = L.w; hl0[(p & 31u) * 256 + t] += (wy * wl[3]) * __uint_as_float(p & 0xFFFFFFE0u); }
        }
        uint4 M = *(const uint4*)(row + xb);
        { unsigned p = M.x; hl1[(p & 31u) * 256 + t] += (wy * wm[0]) * __uint_as_float(p & 0xFFFFFFE0u); }
        { unsigned p = M.y; hl0[(p & 31u) * 256 + t] += (wy * wm[1]) * __uint_as_float(p & 0xFFFFFFE0u); }
        if (cx < 127) {
            { unsigned p = M.z; hl1[(p & 31u) * 256 + t] += (wy * wm[2]) * __uint_as_float(p & 0xFFFFFFE0u); }
            { unsigned p = M.w; hl0[(p & 31u) * 256 + t] += (wy * wm[3]) * __uint_as_float(p & 0xFFFFFFE0u); }
            unsigned p = row[xb + 4];
            hl1[(p & 31u) * 256 + t] += (wy * 0.125f) * __uint_as_float(p & 0xFFFFFFE0u);
        }
    }

    float h[18];
#pragma unroll
    for (int o = 0; o < 18; o++) {
        h[o] = hl0[o * 256 + t] + hl1[o * 256 + t];
        hist[(((size_t)b * 18 + o) * BH + cy) * BW + cx] = h[o];
    }
    float s = 0.0f;
#pragma unroll
    for (int o = 0; o < 9; o++) { float ss = h[o] + h[o + 9]; s += ss * ss; }
    nrm[((size_t)b * BH + cy) * BW + cx] = s;
}

// ---------------- Kernel 3: normalization + features + zero border ----------------
__global__ __launch_bounds__(256) void hog_feat(const float* __restrict__ hist,
                                                const float* __restrict__ nrm,
                                                float* __restrict__ out)
{
    int ox = threadIdx.x;
    int oy = blockIdx.y * 2 + threadIdx.y;
    int b = blockIdx.z;

    if (ox == 0 || ox == BW - 1 || oy == 0 || oy == BH - 1) {
#pragma unroll
        for (int c = 0; c < 31; c++)
            out[(((size_t)b * 31 + c) * BH + oy) * BW + ox] = 0.0f;
        return;
    }

    const float* nb = nrm + (size_t)b * BH * BW;
    float n00 = nb[(size_t)(oy - 1) * BW + ox - 1], n01 = nb[(size_t)(oy - 1) * BW + ox], n02 = nb[(size_t)(oy - 1) * BW + ox + 1];
    float n10 = nb[(size_t)oy * BW + ox - 1],       n11 = nb[(size_t)oy * BW + ox],       n12 = nb[(size_t)oy * BW + ox + 1];
    float n20 = nb[(size_t)(oy + 1) * BW + ox - 1], n21 = nb[(size_t)(oy + 1) * BW + ox], n22 = nb[(size_t)(oy + 1) * BW + ox + 1];

    float T11 = n11 + n21 + n12 + n22;
    float T01 = n01 + n11 + n02 + n12;
    float T10 = n10 + n20 + n11 + n21;
    float T00 = n00 + n10 + n01 + n11;
    float v1 = 1.0f / __fsqrt_rn(T11 + 1e-4f);
    float v2 = 1.0f / __fsqrt_rn(T01 + 1e-4f);
    float v3 = 1.0f / __fsqrt_rn(T10 + 1e-4f);
    float v4 = 1.0f / __fsqrt_rn(T00 + 1e-4f);

    float h[18];
#pragma unroll
    for (int o = 0; o < 18; o++)
        h[o] = hist[(((size_t)b * 18 + o) * BH + oy) * BW + ox];

    float t1 = 0.f, t2 = 0.f, t3 = 0.f, t4 = 0.f;
#pragma unroll
    for (int o = 0; o < 18; o++) {
        float s = h[o];
        float a1 = fminf(s * v1, 0.2f);
        float a2 = fminf(s * v2, 0.2f);
        float a3 = fminf(s * v3, 0.2f);
        float a4 = fminf(s * v4, 0.2f);
        out[(((size_t)b * 31 + o) * BH + oy) * BW + ox] = 0.5f * (a1 + a2 + a3 + a4);
        t1 += a1; t2 += a2; t3 += a3; t4 += a4;
    }
#pragma unroll
    for (int o = 0; o < 9; o++) {
        float ss = h[o] + h[o + 9];
        float a1 = fminf(ss * v1, 0.2f);
        float a2 = fminf(ss * v2, 0.2f);
        float a3 = fminf(ss * v3, 0.2f);
        float a4 = fminf(ss * v4, 0.2f);
        out[(((size_t)b * 31 + 18 + o) * BH + oy) * BW + ox] = 0.5f * (a1 + a2 + a3 + a4);
    }
    out[(((size_t)b * 31 + 27) * BH + oy) * BW + ox] = 0.2357f * t1;
    out[(((size_t)b * 31 + 28) * BH + oy) * BW + ox] = 0.2357f * t2;
    out[(((size_t)b * 31 + 29) * BH + oy) * BW + ox] = 0.2357f * t3;
    out[(((size_t)b * 31 + 30) * BH + oy) * BW + ox] = 0.2357f * t4;
}

extern "C" void kernel_launch(void* const* d_in, const int* in_sizes, int n_in,
                              void* d_out, int out_size, void* d_ws, size_t ws_size,
                              hipStream_t stream)
{
    const float* img = (const float*)d_in[0];
    float* out = (float*)d_out;
    char* ws = (char*)d_ws;

    // workspace layout (256-aligned offsets):
    //   pk   : 16*510*512*4 = 16,711,680  @ 0
    //   hist : 16*18*128*128*4 = 18,874,368 @ 16,715,776
    //   nrm  : 16*128*128*4 = 1,048,576  @ 35,590,144   (end 36,638,720)
    unsigned int* pk = (unsigned int*)ws;
    float* hist      = (float*)(ws + 16715776);
    float* nrm       = (float*)(ws + 35590144);

    dim3 b1(64, 4, 1), g1(2, 128, BATCH);
    hog_grad<<<g1, b1, 0, stream>>>(img, pk);

    dim3 b2(128, 2, 1), g2(1, BH / 2, BATCH);
    hog_hist<<<g2, b2, 0, stream>>>(pk, hist, nrm);
    hog_feat<<<g2, b2, 0, stream>>>(hist, nrm, out);
}

// Round 5
// 118.821 us; speedup vs baseline: 1.6067x; 1.0040x over previous
//
#include <hip/hip_runtime.h>
#include <hip/hip_fp16.h>

#define BATCH 16
#define H 512
#define W 512
#define BH 128
#define BW 128
#define HG 510   // interior rows (buffer rows 0..509 <-> pixel rows 1..510)
#define WG 510
#define PKW 512  // padded row stride of packed intermediate

// pack: (mag_bits & ~31) | o   -- o in [0,18) fits 5 bits; mag rel err ~3e-6
// o is chosen BEFORE truncation, so argmax decisions are bit-identical to ref.

// ---------------- Kernel 1: gradient + orientation, 4x4 px/thread ----------------
// Rolling 6-row window: 6 row-segments serve 16 pixels (vs 3 rows per 4 px
// at 1 row/thread) -> ~2x fewer load instructions, less L1/L2 re-read.
__global__ __launch_bounds__(256) void hog_grad(const float* __restrict__ img,
                                                unsigned int* __restrict__ pk)
{
    int gx = blockIdx.x * 64 + threadIdx.x;   // x-quad 0..127
    int qy = blockIdx.y * 4 + threadIdx.y;    // y-quad 0..127
    int b  = blockIdx.z;
    int x0 = gx * 4;                          // buffer col of px 0 (aligned)
    int y0 = qy * 4;                          // buffer row of output row 0
    bool edge = (x0 < 508);

    const float* im = img + (size_t)b * 3 * H * W;

    float bv[16], bx[16], by[16];
#pragma unroll
    for (int i = 0; i < 16; i++) { bv[i] = -1.f; bx[i] = 0.f; by[i] = 0.f; }

#pragma unroll
    for (int c = 0; c < 3; c++) {
        const float* base = im + (size_t)c * H * W;
        float Wr[6][6];
#pragma unroll
        for (int j = 0; j < 6; j++) {
            int pr = y0 + j; if (pr > 511) pr = 511;   // clamped rows feed only masked outputs
            const float* rowp = base + (size_t)pr * W + x0;
            float4 a = *(const float4*)rowp;
            Wr[j][0] = a.x; Wr[j][1] = a.y; Wr[j][2] = a.z; Wr[j][3] = a.w;
            if (j >= 1 && j <= 4) {
                // f2 spills into row pr+1 when x0==508; OOB only if pr==511 -> guard
                if (edge || pr < 511) {
                    float2 f = *(const float2*)(rowp + 4);
                    Wr[j][4] = f.x; Wr[j][5] = f.y;
                } else { Wr[j][4] = 0.f; Wr[j][5] = 0.f; }
            } else {
                Wr[j][4] = edge ? rowp[4] : 0.0f;   // dy-only rows need col x0+4 only
                Wr[j][5] = 0.f;
            }
        }
#pragma unroll
        for (int r = 0; r < 4; r++) {
#pragma unroll
            for (int i = 0; i < 4; i++) {
                float dx = __fsub_rn(Wr[r + 1][i + 2], Wr[r + 1][i]);
                float dy = __fsub_rn(Wr[r + 2][i + 1], Wr[r][i + 1]);
                float v = __fadd_rn(__fmul_rn(dx, dx), __fmul_rn(dy, dy));
                int k = r * 4 + i;
                if (v > bv[k]) { bv[k] = v; bx[k] = dx; by[k] = dy; }
            }
        }
    }

    const float uu[9] = {1.0f, 0.9397f, 0.766f, 0.5f, 0.1736f, -0.1736f, -0.5f, -0.766f, -0.9397f};
    const float vv[9] = {0.0f, 0.342f, 0.6428f, 0.866f, 0.9848f, 0.9848f, 0.866f, 0.6428f, 0.342f};

#pragma unroll
    for (int r = 0; r < 4; r++) {
        int y = y0 + r;
        if (y >= HG) break;                    // qy=127: rows 2,3 invalid
        unsigned int pkv[4];
#pragma unroll
        for (int i = 0; i < 4; i++) {
            int k = r * 4 + i;
            float mg = __fsqrt_rn(bv[k]);
            float d[9];
#pragma unroll
            for (int o = 0; o < 9; o++)
                d[o] = __fadd_rn(__fmul_rn(uu[o], bx[k]), __fmul_rn(vv[o], by[k]));
            float best = -1e30f; int bo = 0;
#pragma unroll
            for (int o = 0; o < 9; o++) { if (d[o] > best) { best = d[o]; bo = o; } }
#pragma unroll
            for (int o = 0; o < 9; o++) { float nd = -d[o]; if (nd > best) { best = nd; bo = o + 9; } }
            unsigned int v = (__float_as_uint(mg) & 0xFFFFFFE0u) | (unsigned int)bo;
            pkv[i] = (x0 + i < WG) ? v : 0u;   // zero pad cols 510/511
        }
        uint4 o4 = make_uint4(pkv[0], pkv[1], pkv[2], pkv[3]);
        *(uint4*)(pk + ((size_t)b * HG + y) * PKW + x0) = o4;
    }
}

// ---------------- Kernel 2: per-cell 8x8 bilinear gather -> hist(fp16x2) + norm ----------------
// Plain LDS read-add-write (LDS fp32 atomics ~66 cyc/wave-instr on gfx950 -- R3).
// Two private buffers alternated per pixel (R4). Output: bins (o, o+9) packed
// into one half2 dword -> hist traffic halved, k3 reads halved.
__global__ __launch_bounds__(256) void hog_hist(const unsigned int* __restrict__ pk,
                                                __half2* __restrict__ hist,
                                                float* __restrict__ nrm)
{
    __shared__ float hl0[18 * 256];
    __shared__ float hl1[18 * 256];
    int cx = threadIdx.x;                   // 0..127
    int cy = blockIdx.y * 2 + threadIdx.y;  // 0..127
    int b = blockIdx.z;
    int t = threadIdx.y * 128 + cx;

#pragma unroll
    for (int o = 0; o < 18; o++) { hl0[o * 256 + t] = 0.0f; hl1[o * 256 + t] = 0.0f; }
    // per-thread private columns: no barrier; bank = t%32 -> 2-way (free)

    const float wt[8] = {0.125f, 0.375f, 0.625f, 0.875f, 0.875f, 0.625f, 0.375f, 0.125f};
    const float wl[4] = {0.0f, 0.125f, 0.375f, 0.625f};   // pixels 4c-4..4c-1
    const float wm[4] = {0.875f, 0.875f, 0.625f, 0.375f}; // pixels 4c..4c+3

    const unsigned int* pb = pk + (size_t)b * HG * PKW;
    int ry0 = 4 * cy - 3;
    int xb = 4 * cx;

#pragma unroll
    for (int ky = 0; ky < 8; ky++) {
        int ry = ry0 + ky;
        if ((unsigned)ry >= (unsigned)HG) continue;  // wave-uniform
        float wy = wt[ky];
        const unsigned int* row = pb + (size_t)ry * PKW;
        if (cx > 0) {
            uint4 L = *(const uint4*)(row + xb - 4);
            { unsigned p = L.y; hl0[(p & 31u) * 256 + t] += (wy * wl[1]) * __uint_as_float(p & 0xFFFFFFE0u); }
            { unsigned p = L.z; hl1[(p & 31u) * 256 + t] += (wy * wl[2]) * __uint_as_float(p & 0xFFFFFFE0u); }
            { unsigned p = L.w; hl0[(p & 31u) * 256 + t] += (wy * wl[3]) * __uint_as_float(p & 0xFFFFFFE0u); }
        }
        uint4 M = *(const uint4*)(row + xb);
        { unsigned p = M.x; hl1[(p & 31u) * 256 + t] += (wy * wm[0]) * __uint_as_float(p & 0xFFFFFFE0u); }
        { unsigned p = M.y; hl0[(p & 31u) * 256 + t] += (wy * wm[1]) * __uint_as_float(p & 0xFFFFFFE0u); }
        if (cx < 127) {
            { unsigned p = M.z; hl1[(p & 31u) * 256 + t] += (wy * wm[2]) * __uint_as_float(p & 0xFFFFFFE0u); }
            { unsigned p = M.w; hl0[(p & 31u) * 256 + t] += (wy * wm[3]) * __uint_as_float(p & 0xFFFFFFE0u); }
            unsigned p = row[xb + 4];
            hl1[(p & 31u) * 256 + t] += (wy * 0.125f) * __uint_as_float(p & 0xFFFFFFE0u);
        }
    }

    float s = 0.0f;
#pragma unroll
    for (int o = 0; o < 9; o++) {
        float lo = hl0[o * 256 + t] + hl1[o * 256 + t];
        float hi = hl0[(o + 9) * 256 + t] + hl1[(o + 9) * 256 + t];
        hist[(((size_t)b * 9 + o) * BH + cy) * BW + cx] = __floats2half2_rn(lo, hi);
        float ss = lo + hi;
        s += ss * ss;
    }
    nrm[((size_t)b * BH + cy) * BW + cx] = s;
}

// ---------------- Kernel 3: normalization + features + zero border ----------------
__global__ __launch_bounds__(256) void hog_feat(const __half2* __restrict__ hist,
                                                const float* __restrict__ nrm,
                                                float* __restrict__ out)
{
    int ox = threadIdx.x;
    int oy = blockIdx.y * 2 + threadIdx.y;
    int b = blockIdx.z;

    if (ox == 0 || ox == BW - 1 || oy == 0 || oy == BH - 1) {
#pragma unroll
        for (int c = 0; c < 31; c++)
            out[(((size_t)b * 31 + c) * BH + oy) * BW + ox] = 0.0f;
        return;
    }

    const float* nb = nrm + (size_t)b * BH * BW;
    float n00 = nb[(size_t)(oy - 1) * BW + ox - 1], n01 = nb[(size_t)(oy - 1) * BW + ox], n02 = nb[(size_t)(oy - 1) * BW + ox + 1];
    float n10 = nb[(size_t)oy * BW + ox - 1],       n11 = nb[(size_t)oy * BW + ox],       n12 = nb[(size_t)oy * BW + ox + 1];
    float n20 = nb[(size_t)(oy + 1) * BW + ox - 1], n21 = nb[(size_t)(oy + 1) * BW + ox], n22 = nb[(size_t)(oy + 1) * BW + ox + 1];

    float T11 = n11 + n21 + n12 + n22;
    float T01 = n01 + n11 + n02 + n12;
    float T10 = n10 + n20 + n11 + n21;
    float T00 = n00 + n10 + n01 + n11;
    float v1 = 1.0f / __fsqrt_rn(T11 + 1e-4f);
    float v2 = 1.0f / __fsqrt_rn(T01 + 1e-4f);
    float v3 = 1.0f / __fsqrt_rn(T10 + 1e-4f);
    float v4 = 1.0f / __fsqrt_rn(T00 + 1e-4f);

    float h[18];
#pragma unroll
    for (int o = 0; o < 9; o++) {
        float2 f = __half22float2(hist[(((size_t)b * 9 + o) * BH + oy) * BW + ox]);
        h[o] = f.x; h[o + 9] = f.y;
    }

    float t1 = 0.f, t2 = 0.f, t3 = 0.f, t4 = 0.f;
#pragma unroll
    for (int o = 0; o < 18; o++) {
        float s = h[o];
        float a1 = fminf(s * v1, 0.2f);
        float a2 = fminf(s * v2, 0.2f);
        float a3 = fminf(s * v3, 0.2f);
        float a4 = fminf(s * v4, 0.2f);
        out[(((size_t)b * 31 + o) * BH + oy) * BW + ox] = 0.5f * (a1 + a2 + a3 + a4);
        t1 += a1; t2 += a2; t3 += a3; t4 += a4;
    }
#pragma unroll
    for (int o = 0; o < 9; o++) {
        float ss = h[o] + h[o + 9];
        float a1 = fminf(ss * v1, 0.2f);
        float a2 = fminf(ss * v2, 0.2f);
        float a3 = fminf(ss * v3, 0.2f);
        float a4 = fminf(ss * v4, 0.2f);
        out[(((size_t)b * 31 + 18 + o) * BH + oy) * BW + ox] = 0.5f * (a1 + a2 + a3 + a4);
    }
    out[(((size_t)b * 31 + 27) * BH + oy) * BW + ox] = 0.2357f * t1;
    out[(((size_t)b * 31 + 28) * BH + oy) * BW + ox] = 0.2357f * t2;
    out[(((size_t)b * 31 + 29) * BH + oy) * BW + ox] = 0.2357f * t3;
    out[(((size_t)b * 31 + 30) * BH + oy) * BW + ox] = 0.2357f * t4;
}

extern "C" void kernel_launch(void* const* d_in, const int* in_sizes, int n_in,
                              void* d_out, int out_size, void* d_ws, size_t ws_size,
                              hipStream_t stream)
{
    const float* img = (const float*)d_in[0];
    float* out = (float*)d_out;
    char* ws = (char*)d_ws;

    // workspace layout (256-aligned offsets):
    //   pk   : 16*510*512*4 = 16,711,680  @ 0
    //   hist : 16*9*128*128*4 = 9,437,184 @ 16,715,776  (half2-packed bins o|o+9)
    //   nrm  : 16*128*128*4 = 1,048,576  @ 26,152,960   (end 27,201,536)
    unsigned int* pk = (unsigned int*)ws;
    __half2* hist    = (__half2*)(ws + 16715776);
    float* nrm       = (float*)(ws + 26152960);

    dim3 b1(64, 4, 1), g1(2, 32, BATCH);
    hog_grad<<<g1, b1, 0, stream>>>(img, pk);

    dim3 b2(128, 2, 1), g2(1, BH / 2, BATCH);
    hog_hist<<<g2, b2, 0, stream>>>(pk, hist, nrm);
    hog_feat<<<g2, b2, 0, stream>>>(hist, nrm, out);
}